// Round 1
// baseline (18.169 us; speedup 1.0000x reference)
//
#include <hip/hip_runtime.h>

// Problem constants (fixed by setup_inputs): probs [N,T,K] f32, targets [N,L] int
constexpr int N_ = 32;
constexpr int T_ = 256;
constexpr int K_ = 8000;
constexpr int L_ = 64;

// Kernel 1: one block per (n,l) pair. 256 threads; thread t reads
// probs[n, t, k] where k = targets[n,l]; block-reduce the column sum,
// thread 0 writes -log(mean + 1e-10) to partial[n*L + l].
__global__ __launch_bounds__(256) void ACE_colsum_log(
    const float* __restrict__ probs,
    const int* __restrict__ targets,
    float* __restrict__ partial) {
    const int l = blockIdx.x;          // 0..L-1
    const int n = blockIdx.y;          // 0..N-1
    const int t = threadIdx.x;         // 0..T-1 (== 256 threads)

    const int k = targets[n * L_ + l];
    const size_t idx = ((size_t)(n * T_ + t)) * (size_t)K_ + (size_t)k;
    float v = probs[idx];

    // wave (64-lane) butterfly reduce
    #pragma unroll
    for (int off = 32; off > 0; off >>= 1)
        v += __shfl_down(v, off, 64);

    __shared__ float wsum[4];
    const int wid = t >> 6;
    const int lane = t & 63;
    if (lane == 0) wsum[wid] = v;
    __syncthreads();

    if (t == 0) {
        const float s = wsum[0] + wsum[1] + wsum[2] + wsum[3];
        const float meanp = s * (1.0f / (float)T_) + 1e-10f;
        partial[n * L_ + l] = -logf(meanp);
    }
}

// Kernel 2: single block reduces the N*L partials and applies 1/(N*T).
__global__ __launch_bounds__(256) void ACE_final_reduce(
    const float* __restrict__ partial,
    float* __restrict__ out) {
    const int tid = threadIdx.x;       // 256 threads
    float s = 0.0f;
    #pragma unroll
    for (int i = tid; i < N_ * L_; i += 256)
        s += partial[i];

    #pragma unroll
    for (int off = 32; off > 0; off >>= 1)
        s += __shfl_down(s, off, 64);

    __shared__ float wsum[4];
    if ((tid & 63) == 0) wsum[tid >> 6] = s;
    __syncthreads();

    if (tid == 0) {
        const float total = wsum[0] + wsum[1] + wsum[2] + wsum[3];
        out[0] = total * (1.0f / ((float)N_ * (float)T_));
    }
}

extern "C" void kernel_launch(void* const* d_in, const int* in_sizes, int n_in,
                              void* d_out, int out_size, void* d_ws, size_t ws_size,
                              hipStream_t stream) {
    const float* probs = (const float*)d_in[0];
    const int* targets = (const int*)d_in[1];
    float* out = (float*)d_out;
    float* partial = (float*)d_ws;     // needs N*L*4 = 8192 bytes

    dim3 grid1(L_, N_);
    ACE_colsum_log<<<grid1, 256, 0, stream>>>(probs, targets, partial);
    ACE_final_reduce<<<1, 256, 0, stream>>>(partial, out);
}